// Round 1
// baseline (1539.536 us; speedup 1.0000x reference)
//
#include <hip/hip_runtime.h>

#define EMB 64

// ---------------- utility kernels ----------------

__global__ void zero_kernel(float4* __restrict__ p, long n4) {
    long i = (long)blockIdx.x * blockDim.x + threadIdx.x;
    if (i < n4) p[i] = make_float4(0.f, 0.f, 0.f, 0.f);
}

__global__ void add2_kernel(const float4* __restrict__ a, const float4* __restrict__ b,
                            float4* __restrict__ o, long n4) {
    long i = (long)blockIdx.x * blockDim.x + threadIdx.x;
    if (i < n4) {
        float4 va = a[i], vb = b[i];
        o[i] = make_float4(va.x + vb.x, va.y + vb.y, va.z + vb.z, va.w + vb.w);
    }
}

__global__ void addacc_kernel(float4* __restrict__ o, const float4* __restrict__ a, long n4) {
    long i = (long)blockIdx.x * blockDim.x + threadIdx.x;
    if (i < n4) {
        float4 vo = o[i], va = a[i];
        o[i] = make_float4(vo.x + va.x, vo.y + va.y, vo.z + va.z, vo.w + va.w);
    }
}

__global__ void finish_kernel(float4* __restrict__ o, const float4* __restrict__ a,
                              long n4, float s) {
    long i = (long)blockIdx.x * blockDim.x + threadIdx.x;
    if (i < n4) {
        float4 vo = o[i], va = a[i];
        o[i] = make_float4((vo.x + va.x) * s, (vo.y + va.y) * s,
                           (vo.z + va.z) * s, (vo.w + va.w) * s);
    }
}

// ---------------- feature fusion ----------------

__global__ void fuse_users_kernel(const float* __restrict__ feat,       // [U,15]
                                  const int* __restrict__ cidx,
                                  const int* __restrict__ sidx,
                                  const float* __restrict__ emb_w,      // [U,64]
                                  const float* __restrict__ Wn,         // [64,12]
                                  const float* __restrict__ bn,         // [64]
                                  const float* __restrict__ Wv,         // [64,3]
                                  const float* __restrict__ bv,         // [64]
                                  const float* __restrict__ color_w,    // [22,64]
                                  const float* __restrict__ size_w,     // [18,64]
                                  float* __restrict__ x,                // [N,64], users at rows 0..U
                                  int U) {
    int t = blockIdx.x * blockDim.x + threadIdx.x;
    int u = t >> 6, d = t & 63;
    if (u >= U) return;
    const float* f = feat + (size_t)u * 15;
    float acc = emb_w[(size_t)u * EMB + d] + bn[d] + bv[d];
#pragma unroll
    for (int k = 0; k < 12; ++k) acc = fmaf(f[k], Wn[d * 12 + k], acc);
#pragma unroll
    for (int k = 0; k < 3; ++k) acc = fmaf(f[12 + k], Wv[d * 3 + k], acc);
    acc += color_w[(size_t)cidx[u] * EMB + d];
    acc += size_w[(size_t)sidx[u] * EMB + d];
    x[(size_t)u * EMB + d] = acc;
}

__global__ void fuse_items_kernel(const float* __restrict__ feat,       // [I,17]
                                  const float* __restrict__ emb_w,      // [I,64]
                                  const float* __restrict__ Wn,         // [64,5]
                                  const float* __restrict__ bn,         // [64]
                                  const float* __restrict__ Wv,         // [64,12]
                                  const float* __restrict__ bv,         // [64]
                                  float* __restrict__ x,                // [N,64], items at rows U..U+I
                                  int I, int U) {
    int t = blockIdx.x * blockDim.x + threadIdx.x;
    int i = t >> 6, d = t & 63;
    if (i >= I) return;
    const float* f = feat + (size_t)i * 17;
    float acc = emb_w[(size_t)i * EMB + d] + bn[d] + bv[d];
#pragma unroll
    for (int k = 0; k < 5; ++k) acc = fmaf(f[k], Wn[d * 5 + k], acc);
#pragma unroll
    for (int k = 0; k < 12; ++k) acc = fmaf(f[5 + k], Wv[d * 12 + k], acc);
    x[(size_t)(U + i) * EMB + d] = acc;
}

// ---------------- graph plumbing ----------------

__global__ void degree_kernel(const int* __restrict__ col, float* __restrict__ deg, int E) {
    int e = blockIdx.x * blockDim.x + threadIdx.x;
    if (e < E) atomicAdd(&deg[col[e]], 1.0f);
}

__global__ void dis_kernel(const float* __restrict__ deg, float* __restrict__ dis, int N) {
    int n = blockIdx.x * blockDim.x + threadIdx.x;
    if (n < N) {
        float dv = deg[n];
        dis[n] = dv > 0.f ? rsqrtf(dv) : 0.f;
    }
}

__global__ void norm_kernel(const int* __restrict__ row, const int* __restrict__ col,
                            const float* __restrict__ dis, float* __restrict__ nrm, int E) {
    int e = blockIdx.x * blockDim.x + threadIdx.x;
    if (e < E) nrm[e] = dis[row[e]] * dis[col[e]];
}

// thread = (edge, dim): 64 lanes per edge, contiguous atomic targets
__global__ void propagate_kernel(const int* __restrict__ row, const int* __restrict__ col,
                                 const float* __restrict__ nrm,
                                 const float* __restrict__ src, float* __restrict__ dst,
                                 int E) {
    long t = (long)blockIdx.x * blockDim.x + threadIdx.x;
    int e = (int)(t >> 6);
    int d = (int)(t & 63);
    if (e >= E) return;
    int r = row[e], c = col[e];
    float v = nrm[e] * src[(size_t)r * EMB + d];
    atomicAdd(&dst[(size_t)c * EMB + d], v);
}

// ---------------- launch ----------------

extern "C" void kernel_launch(void* const* d_in, const int* in_sizes, int n_in,
                              void* d_out, int out_size, void* d_ws, size_t ws_size,
                              hipStream_t stream) {
    const int*   edge       = (const int*)d_in[0];
    const float* user_feat  = (const float*)d_in[1];
    const int*   cidx       = (const int*)d_in[2];
    const int*   sidx       = (const int*)d_in[3];
    const float* item_feat  = (const float*)d_in[4];
    const float* user_emb_w = (const float*)d_in[5];
    const float* item_emb_w = (const float*)d_in[6];
    const float* uWn        = (const float*)d_in[7];
    const float* ubn        = (const float*)d_in[8];
    const float* uWv        = (const float*)d_in[9];
    const float* ubv        = (const float*)d_in[10];
    const float* color_w    = (const float*)d_in[11];
    const float* size_w     = (const float*)d_in[12];
    const float* iWn        = (const float*)d_in[13];
    const float* ibn        = (const float*)d_in[14];
    const float* iWv        = (const float*)d_in[15];
    const float* ibv        = (const float*)d_in[16];

    const int E = in_sizes[0] / 2;
    const int U = in_sizes[5] / EMB;
    const int I = in_sizes[6] / EMB;
    const int N = U + I;

    const int* row = edge;
    const int* col = edge + E;

    float* out = (float*)d_out;

    // workspace layout
    float* bufA = (float*)d_ws;                       // [N*64]  x / acc2
    float* bufB = bufA + (size_t)N * EMB;             // [N*64]  acc1 / acc3
    float* nrm  = bufB + (size_t)N * EMB;             // [E]
    float* deg  = nrm + E;                            // [N]
    float* dis  = deg + N;                            // [N]

    const long nv   = (long)N * EMB;      // 9.6M floats
    const long nv4  = nv / 4;
    const int  TB   = 256;
    const int  gV4  = (int)((nv4 + TB - 1) / TB);
    const int  gRow = (int)(((long)N * EMB + TB - 1) / TB);   // (u,d) threads
    const int  gE   = (E + TB - 1) / TB;
    const int  gN   = (N + TB - 1) / TB;
    const long tE64 = (long)E * 64;
    const int  gE64 = (int)((tE64 + TB - 1) / TB);

    // 1. fuse features -> bufA (= x)
    {
        int gU = (int)(((long)U * EMB + TB - 1) / TB);
        fuse_users_kernel<<<gU, TB, 0, stream>>>(user_feat, cidx, sidx, user_emb_w,
                                                 uWn, ubn, uWv, ubv, color_w, size_w,
                                                 bufA, U);
        int gI = (int)(((long)I * EMB + TB - 1) / TB);
        fuse_items_kernel<<<gI, TB, 0, stream>>>(item_feat, item_emb_w,
                                                 iWn, ibn, iWv, ibv, bufA, I, U);
    }

    // 2. degree -> dis -> norm
    zero_kernel<<<(N + 4 * TB - 1) / (4 * TB), TB, 0, stream>>>((float4*)deg, (N + 3) / 4);
    degree_kernel<<<gE, TB, 0, stream>>>(col, deg, E);
    dis_kernel<<<gN, TB, 0, stream>>>(deg, dis, N);
    norm_kernel<<<gE, TB, 0, stream>>>(row, col, dis, nrm, E);

    // 3. layer 1: acc1 = P(x) into bufB
    zero_kernel<<<gV4, TB, 0, stream>>>((float4*)bufB, nv4);
    propagate_kernel<<<gE64, TB, 0, stream>>>(row, col, nrm, bufA, bufB, E);
    // out = x + acc1
    add2_kernel<<<gV4, TB, 0, stream>>>((const float4*)bufA, (const float4*)bufB,
                                        (float4*)out, nv4);

    // 4. layer 2: acc2 = P(acc1) into bufA
    zero_kernel<<<gV4, TB, 0, stream>>>((float4*)bufA, nv4);
    propagate_kernel<<<gE64, TB, 0, stream>>>(row, col, nrm, bufB, bufA, E);
    addacc_kernel<<<gV4, TB, 0, stream>>>((float4*)out, (const float4*)bufA, nv4);

    // 5. layer 3: acc3 = P(acc2) into bufB
    zero_kernel<<<gV4, TB, 0, stream>>>((float4*)bufB, nv4);
    propagate_kernel<<<gE64, TB, 0, stream>>>(row, col, nrm, bufA, bufB, E);
    // out = (out + acc3) / 4
    finish_kernel<<<gV4, TB, 0, stream>>>((float4*)out, (const float4*)bufB, nv4, 0.25f);

    (void)gRow; (void)n_in; (void)out_size; (void)ws_size;
}

// Round 2
// 846.691 us; speedup vs baseline: 1.8183x; 1.8183x over previous
//
#include <hip/hip_runtime.h>

#define EMB 64

// ================= utility =================

__global__ void zero_u32_kernel(unsigned* __restrict__ p, int n) {
    int i = blockIdx.x * blockDim.x + threadIdx.x;
    if (i < n) p[i] = 0u;
}

// ================= feature fusion =================
// writes plain x into `total` (=d_out) and dis-premultiplied y into `y0`

__global__ void fuse_users_kernel(const float* __restrict__ feat,       // [U,15]
                                  const int* __restrict__ cidx,
                                  const int* __restrict__ sidx,
                                  const float* __restrict__ emb_w,      // [U,64]
                                  const float* __restrict__ Wn,         // [64,12]
                                  const float* __restrict__ bn,
                                  const float* __restrict__ Wv,         // [64,3]
                                  const float* __restrict__ bv,
                                  const float* __restrict__ color_w,    // [22,64]
                                  const float* __restrict__ size_w,     // [18,64]
                                  const float* __restrict__ dis,        // [N]
                                  float* __restrict__ total,            // [N,64]
                                  float* __restrict__ y0,               // [N,64]
                                  int U) {
    int t = blockIdx.x * blockDim.x + threadIdx.x;
    int u = t >> 6, d = t & 63;
    if (u >= U) return;
    const float* f = feat + (size_t)u * 15;
    float acc = emb_w[(size_t)u * EMB + d] + bn[d] + bv[d];
#pragma unroll
    for (int k = 0; k < 12; ++k) acc = fmaf(f[k], Wn[d * 12 + k], acc);
#pragma unroll
    for (int k = 0; k < 3; ++k) acc = fmaf(f[12 + k], Wv[d * 3 + k], acc);
    acc += color_w[(size_t)cidx[u] * EMB + d];
    acc += size_w[(size_t)sidx[u] * EMB + d];
    size_t o = (size_t)u * EMB + d;
    total[o] = acc;
    y0[o] = acc * dis[u];
}

__global__ void fuse_items_kernel(const float* __restrict__ feat,       // [I,17]
                                  const float* __restrict__ emb_w,      // [I,64]
                                  const float* __restrict__ Wn,         // [64,5]
                                  const float* __restrict__ bn,
                                  const float* __restrict__ Wv,         // [64,12]
                                  const float* __restrict__ bv,
                                  const float* __restrict__ dis,        // [N]
                                  float* __restrict__ total,
                                  float* __restrict__ y0,
                                  int I, int U) {
    int t = blockIdx.x * blockDim.x + threadIdx.x;
    int i = t >> 6, d = t & 63;
    if (i >= I) return;
    const float* f = feat + (size_t)i * 17;
    float acc = emb_w[(size_t)i * EMB + d] + bn[d] + bv[d];
#pragma unroll
    for (int k = 0; k < 5; ++k) acc = fmaf(f[k], Wn[d * 5 + k], acc);
#pragma unroll
    for (int k = 0; k < 12; ++k) acc = fmaf(f[5 + k], Wv[d * 12 + k], acc);
    int n = U + i;
    size_t o = (size_t)n * EMB + d;
    total[o] = acc;
    y0[o] = acc * dis[n];
}

// ================= graph plumbing (CSR build) =================

__global__ void hist_kernel(const int* __restrict__ col, unsigned* __restrict__ cnt, int E) {
    int e = blockIdx.x * blockDim.x + threadIdx.x;
    if (e < E) atomicAdd(&cnt[col[e]], 1u);
}

__global__ void dis_kernel(const unsigned* __restrict__ cnt, float* __restrict__ dis, int N) {
    int n = blockIdx.x * blockDim.x + threadIdx.x;
    if (n < N) {
        unsigned c = cnt[n];
        dis[n] = c > 0u ? rsqrtf((float)c) : 0.f;
    }
}

// exclusive scan of cnt[N] -> rowptr[N] (+ rowptr[N]=E later), 1024 elems/block
__global__ void scan_block_kernel(const unsigned* __restrict__ cnt, int N,
                                  unsigned* __restrict__ excl, unsigned* __restrict__ bsum) {
    __shared__ unsigned sh[256];
    int t = threadIdx.x;
    int base = blockIdx.x * 1024 + t * 4;
    unsigned v0 = 0, v1 = 0, v2 = 0, v3 = 0;
    if (base + 0 < N) v0 = cnt[base + 0];
    if (base + 1 < N) v1 = cnt[base + 1];
    if (base + 2 < N) v2 = cnt[base + 2];
    if (base + 3 < N) v3 = cnt[base + 3];
    unsigned local = v0 + v1 + v2 + v3;
    sh[t] = local;
    __syncthreads();
    for (int off = 1; off < 256; off <<= 1) {
        unsigned y = (t >= off) ? sh[t - off] : 0u;
        __syncthreads();
        sh[t] += y;
        __syncthreads();
    }
    unsigned prefix = sh[t] - local;   // exclusive within block
    if (t == 255) bsum[blockIdx.x] = sh[255];
    unsigned r = prefix;
    if (base + 0 < N) excl[base + 0] = r; r += v0;
    if (base + 1 < N) excl[base + 1] = r; r += v1;
    if (base + 2 < N) excl[base + 2] = r; r += v2;
    if (base + 3 < N) excl[base + 3] = r; r += v3;
}

__global__ void scan_bsums_kernel(unsigned* __restrict__ bsum, int nB) {
    __shared__ unsigned sh[256];
    int t = threadIdx.x;
    unsigned v = (t < nB) ? bsum[t] : 0u;
    sh[t] = v;
    __syncthreads();
    for (int off = 1; off < 256; off <<= 1) {
        unsigned y = (t >= off) ? sh[t - off] : 0u;
        __syncthreads();
        sh[t] += y;
        __syncthreads();
    }
    if (t < nB) bsum[t] = sh[t] - v;   // exclusive
}

__global__ void scan_finish_kernel(unsigned* __restrict__ rowptr, const unsigned* __restrict__ bsum,
                                   int N, int E) {
    int i = blockIdx.x * blockDim.x + threadIdx.x;
    if (i < N) rowptr[i] += bsum[i >> 10];
    if (i == 0) rowptr[N] = (unsigned)E;
}

__global__ void scatter_kernel(const int* __restrict__ row, const int* __restrict__ col,
                               const unsigned* __restrict__ rowptr, unsigned* __restrict__ cursor,
                               int* __restrict__ srcidx, int E) {
    int e = blockIdx.x * blockDim.x + threadIdx.x;
    if (e < E) {
        int c = col[e];
        unsigned pos = rowptr[c] + atomicAdd(&cursor[c], 1u);
        srcidx[pos] = row[e];
    }
}

// ================= propagation (gather, no atomics) =================
// src holds y = dis * acc_prev. One 64-lane wave per node.
// sum = sum_j src[srcidx[j]*64+d];  a = dis[n]*sum  (this layer's acc value)
// total = (total + a) * scale;  next-layer y = dis[n]*a (if store)

__global__ __launch_bounds__(256) void gather_propagate_kernel(
        const unsigned* __restrict__ rowptr, const int* __restrict__ srcidx,
        const float* __restrict__ dis, const float* __restrict__ src,
        float* __restrict__ ynext, float* __restrict__ total,
        float scale, int N, int store) {
    int n = blockIdx.x * 4 + (threadIdx.x >> 6);
    if (n >= N) return;
    int d = threadIdx.x & 63;
    unsigned beg = rowptr[n], end = rowptr[n + 1];
    float sum = 0.f;
    for (unsigned j = beg; j < end; ++j) {
        int r = srcidx[j];
        sum += src[(size_t)r * EMB + d];
    }
    float dn = dis[n];
    float a = dn * sum;
    size_t o = (size_t)n * EMB + d;
    total[o] = (total[o] + a) * scale;
    if (store) ynext[o] = dn * a;
}

// ================= launch =================

extern "C" void kernel_launch(void* const* d_in, const int* in_sizes, int n_in,
                              void* d_out, int out_size, void* d_ws, size_t ws_size,
                              hipStream_t stream) {
    const int*   edge       = (const int*)d_in[0];
    const float* user_feat  = (const float*)d_in[1];
    const int*   cidx       = (const int*)d_in[2];
    const int*   sidx       = (const int*)d_in[3];
    const float* item_feat  = (const float*)d_in[4];
    const float* user_emb_w = (const float*)d_in[5];
    const float* item_emb_w = (const float*)d_in[6];
    const float* uWn        = (const float*)d_in[7];
    const float* ubn        = (const float*)d_in[8];
    const float* uWv        = (const float*)d_in[9];
    const float* ubv        = (const float*)d_in[10];
    const float* color_w    = (const float*)d_in[11];
    const float* size_w     = (const float*)d_in[12];
    const float* iWn        = (const float*)d_in[13];
    const float* ibn        = (const float*)d_in[14];
    const float* iWv        = (const float*)d_in[15];
    const float* ibv        = (const float*)d_in[16];

    const int E = in_sizes[0] / 2;
    const int U = in_sizes[5] / EMB;
    const int I = in_sizes[6] / EMB;
    const int N = U + I;

    const int* row = edge;
    const int* col = edge + E;

    float* total = (float*)d_out;   // running sum x + a1 + a2 + a3

    // workspace layout (all 4-byte elems)
    float*    bufA   = (float*)d_ws;                    // [N*64] y buffers
    float*    bufB   = bufA + (size_t)N * EMB;          // [N*64]
    int*      srcidx = (int*)(bufB + (size_t)N * EMB);  // [E]
    unsigned* rowptr = (unsigned*)(srcidx + E);         // [N+1]
    unsigned* cnt    = rowptr + (N + 1);                // [N]
    unsigned* cursor = cnt + N;                         // [N]
    float*    dis    = (float*)(cursor + N);            // [N]
    unsigned* bsum   = (unsigned*)(dis + N);            // [<=256]

    const int TB = 256;
    const int gE = (E + TB - 1) / TB;
    const int gN = (N + TB - 1) / TB;
    const int nB = (N + 1023) / 1024;   // scan blocks (147 for N=150k, must be <=256)

    // 1. zero cnt+cursor (contiguous? cnt and cursor are adjacent except rowptr between)
    zero_u32_kernel<<<gN, TB, 0, stream>>>(cnt, N);
    zero_u32_kernel<<<gN, TB, 0, stream>>>(cursor, N);

    // 2. degree histogram -> dis
    hist_kernel<<<gE, TB, 0, stream>>>(col, cnt, E);
    dis_kernel<<<gN, TB, 0, stream>>>(cnt, dis, N);

    // 3. fuse features: total = x, bufA = dis*x   (needs dis)
    {
        int gU = (int)(((long)U * EMB + TB - 1) / TB);
        fuse_users_kernel<<<gU, TB, 0, stream>>>(user_feat, cidx, sidx, user_emb_w,
                                                 uWn, ubn, uWv, ubv, color_w, size_w,
                                                 dis, total, bufA, U);
        int gI = (int)(((long)I * EMB + TB - 1) / TB);
        fuse_items_kernel<<<gI, TB, 0, stream>>>(item_feat, item_emb_w,
                                                 iWn, ibn, iWv, ibv,
                                                 dis, total, bufA, I, U);
    }

    // 4. CSR build: exclusive scan of cnt -> rowptr, then scatter src indices
    scan_block_kernel<<<nB, TB, 0, stream>>>(cnt, N, rowptr, bsum);
    scan_bsums_kernel<<<1, TB, 0, stream>>>(bsum, nB);
    scan_finish_kernel<<<gN, TB, 0, stream>>>(rowptr, bsum, N, E);
    scatter_kernel<<<gE, TB, 0, stream>>>(row, col, rowptr, cursor, srcidx, E);

    // 5. three propagation layers (gather form), total-accumulate fused
    const int gG = (N + 3) / 4;   // 4 nodes (waves) per block
    // layer 1: src=bufA(y0) -> ynext=bufB ; total += a1
    gather_propagate_kernel<<<gG, TB, 0, stream>>>(rowptr, srcidx, dis, bufA, bufB, total,
                                                   1.0f, N, 1);
    // layer 2: src=bufB -> ynext=bufA ; total += a2
    gather_propagate_kernel<<<gG, TB, 0, stream>>>(rowptr, srcidx, dis, bufB, bufA, total,
                                                   1.0f, N, 1);
    // layer 3: src=bufA ; total = (total + a3) * 0.25
    gather_propagate_kernel<<<gG, TB, 0, stream>>>(rowptr, srcidx, dis, bufA, bufB, total,
                                                   0.25f, N, 0);

    (void)n_in; (void)out_size; (void)ws_size;
}

// Round 3
// 507.772 us; speedup vs baseline: 3.0319x; 1.6675x over previous
//
#include <hip/hip_runtime.h>

#define EMB 64

// ================= utility =================

__global__ void zero_u32_kernel(unsigned* __restrict__ p, int n) {
    int i = blockIdx.x * blockDim.x + threadIdx.x;
    if (i < n) p[i] = 0u;
}

// ================= feature fusion =================
// writes plain x into `total` (=d_out) and dis-premultiplied y into `y0`

__global__ void fuse_users_kernel(const float* __restrict__ feat,       // [U,15]
                                  const int* __restrict__ cidx,
                                  const int* __restrict__ sidx,
                                  const float* __restrict__ emb_w,      // [U,64]
                                  const float* __restrict__ Wn,         // [64,12]
                                  const float* __restrict__ bn,
                                  const float* __restrict__ Wv,         // [64,3]
                                  const float* __restrict__ bv,
                                  const float* __restrict__ color_w,    // [22,64]
                                  const float* __restrict__ size_w,     // [18,64]
                                  const float* __restrict__ dis,        // [N]
                                  float* __restrict__ total,            // [N,64]
                                  float* __restrict__ y0,               // [N,64]
                                  int U) {
    int t = blockIdx.x * blockDim.x + threadIdx.x;
    int u = t >> 6, d = t & 63;
    if (u >= U) return;
    const float* f = feat + (size_t)u * 15;
    float acc = emb_w[(size_t)u * EMB + d] + bn[d] + bv[d];
#pragma unroll
    for (int k = 0; k < 12; ++k) acc = fmaf(f[k], Wn[d * 12 + k], acc);
#pragma unroll
    for (int k = 0; k < 3; ++k) acc = fmaf(f[12 + k], Wv[d * 3 + k], acc);
    acc += color_w[(size_t)cidx[u] * EMB + d];
    acc += size_w[(size_t)sidx[u] * EMB + d];
    size_t o = (size_t)u * EMB + d;
    total[o] = acc;
    y0[o] = acc * dis[u];
}

__global__ void fuse_items_kernel(const float* __restrict__ feat,       // [I,17]
                                  const float* __restrict__ emb_w,      // [I,64]
                                  const float* __restrict__ Wn,         // [64,5]
                                  const float* __restrict__ bn,
                                  const float* __restrict__ Wv,         // [64,12]
                                  const float* __restrict__ bv,
                                  const float* __restrict__ dis,        // [N]
                                  float* __restrict__ total,
                                  float* __restrict__ y0,
                                  int I, int U) {
    int t = blockIdx.x * blockDim.x + threadIdx.x;
    int i = t >> 6, d = t & 63;
    if (i >= I) return;
    const float* f = feat + (size_t)i * 17;
    float acc = emb_w[(size_t)i * EMB + d] + bn[d] + bv[d];
#pragma unroll
    for (int k = 0; k < 5; ++k) acc = fmaf(f[k], Wn[d * 5 + k], acc);
#pragma unroll
    for (int k = 0; k < 12; ++k) acc = fmaf(f[5 + k], Wv[d * 12 + k], acc);
    int n = U + i;
    size_t o = (size_t)n * EMB + d;
    total[o] = acc;
    y0[o] = acc * dis[n];
}

// ================= graph plumbing (CSR build) =================

__global__ void hist_kernel(const int* __restrict__ col, unsigned* __restrict__ cnt, int E) {
    int e = blockIdx.x * blockDim.x + threadIdx.x;
    if (e < E) atomicAdd(&cnt[col[e]], 1u);
}

__global__ void dis_kernel(const unsigned* __restrict__ cnt, float* __restrict__ dis, int N) {
    int n = blockIdx.x * blockDim.x + threadIdx.x;
    if (n < N) {
        unsigned c = cnt[n];
        dis[n] = c > 0u ? rsqrtf((float)c) : 0.f;
    }
}

// exclusive scan of cnt[N] -> rowptr[N] (+ rowptr[N]=E later), 1024 elems/block
__global__ void scan_block_kernel(const unsigned* __restrict__ cnt, int N,
                                  unsigned* __restrict__ excl, unsigned* __restrict__ bsum) {
    __shared__ unsigned sh[256];
    int t = threadIdx.x;
    int base = blockIdx.x * 1024 + t * 4;
    unsigned v0 = 0, v1 = 0, v2 = 0, v3 = 0;
    if (base + 0 < N) v0 = cnt[base + 0];
    if (base + 1 < N) v1 = cnt[base + 1];
    if (base + 2 < N) v2 = cnt[base + 2];
    if (base + 3 < N) v3 = cnt[base + 3];
    unsigned local = v0 + v1 + v2 + v3;
    sh[t] = local;
    __syncthreads();
    for (int off = 1; off < 256; off <<= 1) {
        unsigned y = (t >= off) ? sh[t - off] : 0u;
        __syncthreads();
        sh[t] += y;
        __syncthreads();
    }
    unsigned prefix = sh[t] - local;   // exclusive within block
    if (t == 255) bsum[blockIdx.x] = sh[255];
    unsigned r = prefix;
    if (base + 0 < N) excl[base + 0] = r; r += v0;
    if (base + 1 < N) excl[base + 1] = r; r += v1;
    if (base + 2 < N) excl[base + 2] = r; r += v2;
    if (base + 3 < N) excl[base + 3] = r; r += v3;
}

__global__ void scan_bsums_kernel(unsigned* __restrict__ bsum, int nB) {
    __shared__ unsigned sh[256];
    int t = threadIdx.x;
    unsigned v = (t < nB) ? bsum[t] : 0u;
    sh[t] = v;
    __syncthreads();
    for (int off = 1; off < 256; off <<= 1) {
        unsigned y = (t >= off) ? sh[t - off] : 0u;
        __syncthreads();
        sh[t] += y;
        __syncthreads();
    }
    if (t < nB) bsum[t] = sh[t] - v;   // exclusive
}

__global__ void scan_finish_kernel(unsigned* __restrict__ rowptr, const unsigned* __restrict__ bsum,
                                   int N, int E) {
    int i = blockIdx.x * blockDim.x + threadIdx.x;
    if (i < N) rowptr[i] += bsum[i >> 10];
    if (i == 0) rowptr[N] = (unsigned)E;
}

__global__ void scatter_kernel(const int* __restrict__ row, const int* __restrict__ col,
                               const unsigned* __restrict__ rowptr, unsigned* __restrict__ cursor,
                               int* __restrict__ srcidx, int E) {
    int e = blockIdx.x * blockDim.x + threadIdx.x;
    if (e < E) {
        int c = col[e];
        unsigned pos = rowptr[c] + atomicAdd(&cursor[c], 1u);
        srcidx[pos] = row[e];
    }
}

// ================= propagation (gather, no atomics) =================
// src holds y = dis * acc_prev. One 64-lane wave per node, lane = dim.
// 8-wide unrolled edge loop: 8 independent row loads in flight per wave.

__global__ __launch_bounds__(256) void gather_propagate_kernel(
        const unsigned* __restrict__ rowptr, const int* __restrict__ srcidx,
        const float* __restrict__ dis, const float* __restrict__ src,
        float* __restrict__ ynext, float* __restrict__ total,
        float scale, int N, int store) {
    int n = blockIdx.x * 4 + (threadIdx.x >> 6);
    if (n >= N) return;
    int d = threadIdx.x & 63;
    unsigned beg = rowptr[n], end = rowptr[n + 1];
    float sum = 0.f;
    if (beg < end) {
        unsigned last = end - 1;
        for (unsigned j = beg; j < end; j += 8) {
            int r[8];
#pragma unroll
            for (int k = 0; k < 8; ++k) {
                unsigned jk = j + (unsigned)k;
                r[k] = srcidx[jk < end ? jk : last];   // clamped: always valid
            }
            float v[8];
#pragma unroll
            for (int k = 0; k < 8; ++k)
                v[k] = src[(unsigned)r[k] * 64u + (unsigned)d];
            // tree add, tail entries select-zeroed (duplicate clamped loads hit L1)
            float s0 = v[0];
            s0 += (j + 1u < end) ? v[1] : 0.f;
            float s1 = (j + 2u < end) ? v[2] : 0.f;
            s1 += (j + 3u < end) ? v[3] : 0.f;
            float s2 = (j + 4u < end) ? v[4] : 0.f;
            s2 += (j + 5u < end) ? v[5] : 0.f;
            float s3 = (j + 6u < end) ? v[6] : 0.f;
            s3 += (j + 7u < end) ? v[7] : 0.f;
            sum += (s0 + s1) + (s2 + s3);
        }
    }
    float dn = dis[n];
    float a = dn * sum;
    size_t o = (size_t)n * EMB + d;
    total[o] = (total[o] + a) * scale;
    if (store) ynext[o] = dn * a;
}

// ================= launch =================

extern "C" void kernel_launch(void* const* d_in, const int* in_sizes, int n_in,
                              void* d_out, int out_size, void* d_ws, size_t ws_size,
                              hipStream_t stream) {
    const int*   edge       = (const int*)d_in[0];
    const float* user_feat  = (const float*)d_in[1];
    const int*   cidx       = (const int*)d_in[2];
    const int*   sidx       = (const int*)d_in[3];
    const float* item_feat  = (const float*)d_in[4];
    const float* user_emb_w = (const float*)d_in[5];
    const float* item_emb_w = (const float*)d_in[6];
    const float* uWn        = (const float*)d_in[7];
    const float* ubn        = (const float*)d_in[8];
    const float* uWv        = (const float*)d_in[9];
    const float* ubv        = (const float*)d_in[10];
    const float* color_w    = (const float*)d_in[11];
    const float* size_w     = (const float*)d_in[12];
    const float* iWn        = (const float*)d_in[13];
    const float* ibn        = (const float*)d_in[14];
    const float* iWv        = (const float*)d_in[15];
    const float* ibv        = (const float*)d_in[16];

    const int E = in_sizes[0] / 2;
    const int U = in_sizes[5] / EMB;
    const int I = in_sizes[6] / EMB;
    const int N = U + I;

    const int* row = edge;
    const int* col = edge + E;

    float* total = (float*)d_out;   // running sum x + a1 + a2 + a3

    // workspace layout (all 4-byte elems); cnt & cursor adjacent for single zero
    float*    bufA   = (float*)d_ws;                    // [N*64] y buffers
    float*    bufB   = bufA + (size_t)N * EMB;          // [N*64]
    int*      srcidx = (int*)(bufB + (size_t)N * EMB);  // [E]
    unsigned* rowptr = (unsigned*)(srcidx + E);         // [N+1]
    unsigned* cnt    = rowptr + (N + 1);                // [N]
    unsigned* cursor = cnt + N;                         // [N]  (contiguous with cnt)
    float*    dis    = (float*)(cursor + N);            // [N]
    unsigned* bsum   = (unsigned*)(dis + N);            // [<=256]

    const int TB = 256;
    const int gE = (E + TB - 1) / TB;
    const int gN = (N + TB - 1) / TB;
    const int g2N = (2 * N + TB - 1) / TB;
    const int nB = (N + 1023) / 1024;   // scan blocks (147 for N=150k, must be <=256)

    // 1. zero cnt+cursor in one pass (adjacent)
    zero_u32_kernel<<<g2N, TB, 0, stream>>>(cnt, 2 * N);

    // 2. degree histogram -> dis
    hist_kernel<<<gE, TB, 0, stream>>>(col, cnt, E);
    dis_kernel<<<gN, TB, 0, stream>>>(cnt, dis, N);

    // 3. fuse features: total = x, bufA = dis*x   (needs dis)
    {
        int gU = (int)(((long)U * EMB + TB - 1) / TB);
        fuse_users_kernel<<<gU, TB, 0, stream>>>(user_feat, cidx, sidx, user_emb_w,
                                                 uWn, ubn, uWv, ubv, color_w, size_w,
                                                 dis, total, bufA, U);
        int gI = (int)(((long)I * EMB + TB - 1) / TB);
        fuse_items_kernel<<<gI, TB, 0, stream>>>(item_feat, item_emb_w,
                                                 iWn, ibn, iWv, ibv,
                                                 dis, total, bufA, I, U);
    }

    // 4. CSR build: exclusive scan of cnt -> rowptr, then scatter src indices
    scan_block_kernel<<<nB, TB, 0, stream>>>(cnt, N, rowptr, bsum);
    scan_bsums_kernel<<<1, TB, 0, stream>>>(bsum, nB);
    scan_finish_kernel<<<gN, TB, 0, stream>>>(rowptr, bsum, N, E);
    scatter_kernel<<<gE, TB, 0, stream>>>(row, col, rowptr, cursor, srcidx, E);

    // 5. three propagation layers (gather form), total-accumulate fused
    const int gG = (N + 3) / 4;   // 4 nodes (waves) per block
    gather_propagate_kernel<<<gG, TB, 0, stream>>>(rowptr, srcidx, dis, bufA, bufB, total,
                                                   1.0f, N, 1);
    gather_propagate_kernel<<<gG, TB, 0, stream>>>(rowptr, srcidx, dis, bufB, bufA, total,
                                                   1.0f, N, 1);
    gather_propagate_kernel<<<gG, TB, 0, stream>>>(rowptr, srcidx, dis, bufA, bufB, total,
                                                   0.25f, N, 0);

    (void)n_in; (void)out_size; (void)ws_size;
}

// Round 4
// 388.587 us; speedup vs baseline: 3.9619x; 1.3067x over previous
//
#include <hip/hip_runtime.h>

#define EMB 64
#define NBMAX 512     // max buckets (NB = ceil(N/512) = 293 for N=150000)
#define BCAP 8192     // bucket region capacity (mean 6827, +16 sigma)

// ================= utility =================

__global__ void zero_u32_kernel(unsigned* __restrict__ p, int n) {
    int i = blockIdx.x * blockDim.x + threadIdx.x;
    if (i < n) p[i] = 0u;
}

// ================= feature fusion =================

__global__ void fuse_users_kernel(const float* __restrict__ feat,       // [U,15]
                                  const int* __restrict__ cidx,
                                  const int* __restrict__ sidx,
                                  const float* __restrict__ emb_w,      // [U,64]
                                  const float* __restrict__ Wn,         // [64,12]
                                  const float* __restrict__ bn,
                                  const float* __restrict__ Wv,         // [64,3]
                                  const float* __restrict__ bv,
                                  const float* __restrict__ color_w,    // [22,64]
                                  const float* __restrict__ size_w,     // [18,64]
                                  const float* __restrict__ dis,        // [N]
                                  float* __restrict__ total,            // [N,64]
                                  float* __restrict__ y0,               // [N,64]
                                  int U) {
    int t = blockIdx.x * blockDim.x + threadIdx.x;
    int u = t >> 6, d = t & 63;
    if (u >= U) return;
    const float* f = feat + (size_t)u * 15;
    float acc = emb_w[(size_t)u * EMB + d] + bn[d] + bv[d];
#pragma unroll
    for (int k = 0; k < 12; ++k) acc = fmaf(f[k], Wn[d * 12 + k], acc);
#pragma unroll
    for (int k = 0; k < 3; ++k) acc = fmaf(f[12 + k], Wv[d * 3 + k], acc);
    acc += color_w[(size_t)cidx[u] * EMB + d];
    acc += size_w[(size_t)sidx[u] * EMB + d];
    size_t o = (size_t)u * EMB + d;
    total[o] = acc;
    y0[o] = acc * dis[u];
}

__global__ void fuse_items_kernel(const float* __restrict__ feat,       // [I,17]
                                  const float* __restrict__ emb_w,      // [I,64]
                                  const float* __restrict__ Wn,         // [64,5]
                                  const float* __restrict__ bn,
                                  const float* __restrict__ Wv,         // [64,12]
                                  const float* __restrict__ bv,
                                  const float* __restrict__ dis,        // [N]
                                  float* __restrict__ total,
                                  float* __restrict__ y0,
                                  int I, int U) {
    int t = blockIdx.x * blockDim.x + threadIdx.x;
    int i = t >> 6, d = t & 63;
    if (i >= I) return;
    const float* f = feat + (size_t)i * 17;
    float acc = emb_w[(size_t)i * EMB + d] + bn[d] + bv[d];
#pragma unroll
    for (int k = 0; k < 5; ++k) acc = fmaf(f[k], Wn[d * 5 + k], acc);
#pragma unroll
    for (int k = 0; k < 12; ++k) acc = fmaf(f[5 + k], Wv[d * 12 + k], acc);
    int n = U + i;
    size_t o = (size_t)n * EMB + d;
    total[o] = acc;
    y0[o] = acc * dis[n];
}

// ================= bucketed CSR build =================
// pass 1: partition edges into NB col-range buckets (packed row<<9 | col&511)

__global__ __launch_bounds__(256) void partition_kernel(
        const int* __restrict__ row, const int* __restrict__ col,
        unsigned* __restrict__ bcursor, unsigned* __restrict__ bucketbuf,
        int E, int NB) {
    __shared__ unsigned h[NBMAX];
    __shared__ unsigned wbase[NBMAX];
    const int t = threadIdx.x;
    const long chunk = (long)blockIdx.x * BCAP;

    for (int i = t; i < NB; i += 256) h[i] = 0u;
    __syncthreads();
    // phase A: per-WG histogram
    for (int it = 0; it < BCAP / 256; ++it) {
        long e = chunk + (long)it * 256 + t;
        if (e < E) atomicAdd(&h[((unsigned)col[e]) >> 9], 1u);
    }
    __syncthreads();
    // phase B: reserve global space, reset running cursors
    for (int i = t; i < NB; i += 256) {
        unsigned c = h[i];
        wbase[i] = c ? atomicAdd(&bcursor[i], c) : 0u;
    }
    __syncthreads();
    for (int i = t; i < NB; i += 256) h[i] = 0u;
    __syncthreads();
    // phase C: scatter into bucket regions (WG-chunked -> mostly line-merged)
    for (int it = 0; it < BCAP / 256; ++it) {
        long e = chunk + (long)it * 256 + t;
        if (e < E) {
            unsigned c = (unsigned)col[e];
            unsigned b = c >> 9;
            unsigned lpos = atomicAdd(&h[b], 1u);
            unsigned pos = wbase[b] + lpos;
            if (pos < BCAP)
                bucketbuf[(size_t)b * BCAP + pos] = (((unsigned)row[e]) << 9) | (c & 511u);
        }
    }
}

// pass 2: one WG per bucket -> rowptr, dis, srcidx (all writes XCD-local)

__global__ __launch_bounds__(256) void bucket_csr_kernel(
        const unsigned* __restrict__ bcursor,   // final per-bucket counts
        const unsigned* __restrict__ bucketbuf,
        unsigned* __restrict__ rowptr, float* __restrict__ dis,
        int* __restrict__ srcidx, int N, int E, int NB) {
    const int b = blockIdx.x;
    const int t = threadIdx.x;
    __shared__ unsigned red[256];
    __shared__ unsigned hist[512];
    __shared__ unsigned ps[256];

    // base = sum_{i<b} bcursor[i]
    unsigned part = 0;
    for (int i = t; i < b; i += 256) part += bcursor[i];
    red[t] = part;
    __syncthreads();
    for (int off = 128; off > 0; off >>= 1) {
        if (t < off) red[t] += red[t + off];
        __syncthreads();
    }
    const unsigned base = red[0];
    unsigned cntb = bcursor[b];
    if (cntb > BCAP) cntb = BCAP;

    // local histogram over 512 nodes of this bucket
    hist[2 * t] = 0u; hist[2 * t + 1] = 0u;
    __syncthreads();
    const unsigned* buf = bucketbuf + (size_t)b * BCAP;
    for (unsigned j = t; j < cntb; j += 256) atomicAdd(&hist[buf[j] & 511u], 1u);
    __syncthreads();

    // exclusive scan of hist[512] (2 elems/thread + Hillis-Steele over pair sums)
    unsigned h0 = hist[2 * t], h1 = hist[2 * t + 1];
    ps[t] = h0 + h1;
    __syncthreads();
    for (int off = 1; off < 256; off <<= 1) {
        unsigned y = (t >= off) ? ps[t - off] : 0u;
        __syncthreads();
        ps[t] += y;
        __syncthreads();
    }
    unsigned pexcl = ps[t] - (h0 + h1);
    unsigned off0 = pexcl, off1 = pexcl + h0;

    int n0 = (b << 9) + 2 * t, n1 = n0 + 1;
    if (n0 < N) { rowptr[n0] = base + off0; dis[n0] = h0 ? rsqrtf((float)h0) : 0.f; }
    if (n1 < N) { rowptr[n1] = base + off1; dis[n1] = h1 ? rsqrtf((float)h1) : 0.f; }
    if (b == NB - 1 && t == 0) rowptr[N] = (unsigned)E;
    __syncthreads();

    // scatter via LDS cursors; srcidx writes land in one ~27KB window (one XCD)
    hist[2 * t] = off0; hist[2 * t + 1] = off1;
    __syncthreads();
    for (unsigned j = t; j < cntb; j += 256) {
        unsigned p = buf[j];
        unsigned pos = atomicAdd(&hist[p & 511u], 1u);
        srcidx[base + pos] = (int)(p >> 9);
    }
}

// ================= propagation (gather, no atomics) =================
// src holds y = dis * acc_prev. One 64-lane wave per node, lane = dim.
// 8-wide unrolled edge loop; NT loads/stores for streaming data keep L2 for src.

__global__ __launch_bounds__(256) void gather_propagate_kernel(
        const unsigned* __restrict__ rowptr, const int* __restrict__ srcidx,
        const float* __restrict__ dis, const float* __restrict__ src,
        float* __restrict__ ynext, float* __restrict__ total,
        float scale, int N, int store) {
    int n = blockIdx.x * 4 + (threadIdx.x >> 6);
    if (n >= N) return;
    int d = threadIdx.x & 63;
    unsigned beg = rowptr[n], end = rowptr[n + 1];
    float sum = 0.f;
    if (beg < end) {
        unsigned last = end - 1;
        for (unsigned j = beg; j < end; j += 8) {
            int r[8];
#pragma unroll
            for (int k = 0; k < 8; ++k) {
                unsigned jk = j + (unsigned)k;
                r[k] = __builtin_nontemporal_load(&srcidx[jk < end ? jk : last]);
            }
            float v[8];
#pragma unroll
            for (int k = 0; k < 8; ++k)
                v[k] = src[(unsigned)r[k] * 64u + (unsigned)d];
            float s0 = v[0];
            s0 += (j + 1u < end) ? v[1] : 0.f;
            float s1 = (j + 2u < end) ? v[2] : 0.f;
            s1 += (j + 3u < end) ? v[3] : 0.f;
            float s2 = (j + 4u < end) ? v[4] : 0.f;
            s2 += (j + 5u < end) ? v[5] : 0.f;
            float s3 = (j + 6u < end) ? v[6] : 0.f;
            s3 += (j + 7u < end) ? v[7] : 0.f;
            sum += (s0 + s1) + (s2 + s3);
        }
    }
    float dn = dis[n];
    float a = dn * sum;
    size_t o = (size_t)n * EMB + d;
    float tv = __builtin_nontemporal_load(&total[o]);
    __builtin_nontemporal_store((tv + a) * scale, &total[o]);
    if (store) __builtin_nontemporal_store(dn * a, &ynext[o]);
}

// ================= launch =================

extern "C" void kernel_launch(void* const* d_in, const int* in_sizes, int n_in,
                              void* d_out, int out_size, void* d_ws, size_t ws_size,
                              hipStream_t stream) {
    const int*   edge       = (const int*)d_in[0];
    const float* user_feat  = (const float*)d_in[1];
    const int*   cidx       = (const int*)d_in[2];
    const int*   sidx       = (const int*)d_in[3];
    const float* item_feat  = (const float*)d_in[4];
    const float* user_emb_w = (const float*)d_in[5];
    const float* item_emb_w = (const float*)d_in[6];
    const float* uWn        = (const float*)d_in[7];
    const float* ubn        = (const float*)d_in[8];
    const float* uWv        = (const float*)d_in[9];
    const float* ubv        = (const float*)d_in[10];
    const float* color_w    = (const float*)d_in[11];
    const float* size_w     = (const float*)d_in[12];
    const float* iWn        = (const float*)d_in[13];
    const float* ibn        = (const float*)d_in[14];
    const float* iWv        = (const float*)d_in[15];
    const float* ibv        = (const float*)d_in[16];

    const int E = in_sizes[0] / 2;
    const int U = in_sizes[5] / EMB;
    const int I = in_sizes[6] / EMB;
    const int N = U + I;
    const int NB = (N + 511) >> 9;     // 293 buckets

    const int* row = edge;
    const int* col = edge + E;

    float* total = (float*)d_out;      // running sum x + a1 + a2 + a3

    // workspace layout; bucketbuf aliases bufB (disjoint lifetimes)
    float*    bufA      = (float*)d_ws;                    // [N*64] y buffers
    float*    bufB      = bufA + (size_t)N * EMB;          // [N*64]; also bucketbuf
    unsigned* bucketbuf = (unsigned*)bufB;                 // [NB*BCAP] (pass1->pass2 only)
    int*      srcidx    = (int*)(bufB + (size_t)N * EMB);  // [E]
    unsigned* rowptr    = (unsigned*)(srcidx + E);         // [N+1]
    float*    dis       = (float*)(rowptr + N + 1);        // [N]
    unsigned* bcursor   = (unsigned*)(dis + N);            // [NB]

    const int TB = 256;

    // 1. CSR build (also produces dis)
    zero_u32_kernel<<<(NB + TB - 1) / TB, TB, 0, stream>>>(bcursor, NB);
    const int gP = (E + BCAP - 1) / BCAP;
    partition_kernel<<<gP, TB, 0, stream>>>(row, col, bcursor, bucketbuf, E, NB);
    bucket_csr_kernel<<<NB, TB, 0, stream>>>(bcursor, bucketbuf, rowptr, dis, srcidx,
                                             N, E, NB);

    // 2. fuse features: total = x, bufA = dis*x
    {
        int gU = (int)(((long)U * EMB + TB - 1) / TB);
        fuse_users_kernel<<<gU, TB, 0, stream>>>(user_feat, cidx, sidx, user_emb_w,
                                                 uWn, ubn, uWv, ubv, color_w, size_w,
                                                 dis, total, bufA, U);
        int gI = (int)(((long)I * EMB + TB - 1) / TB);
        fuse_items_kernel<<<gI, TB, 0, stream>>>(item_feat, item_emb_w,
                                                 iWn, ibn, iWv, ibv,
                                                 dis, total, bufA, I, U);
    }

    // 3. three propagation layers (gather form), total-accumulate fused
    const int gG = (N + 3) / 4;   // 4 nodes (waves) per block
    gather_propagate_kernel<<<gG, TB, 0, stream>>>(rowptr, srcidx, dis, bufA, bufB, total,
                                                   1.0f, N, 1);
    gather_propagate_kernel<<<gG, TB, 0, stream>>>(rowptr, srcidx, dis, bufB, bufA, total,
                                                   1.0f, N, 1);
    gather_propagate_kernel<<<gG, TB, 0, stream>>>(rowptr, srcidx, dis, bufA, bufB, total,
                                                   0.25f, N, 0);

    (void)n_in; (void)out_size; (void)ws_size;
}

// Round 5
// 357.971 us; speedup vs baseline: 4.3007x; 1.0855x over previous
//
#include <hip/hip_runtime.h>

#define EMB 64
#define NBMAX 512      // max buckets (NB = ceil(N/512) = 293 for N=150000)
#define BCAP 8192      // bucket edge capacity (mean 6827, +16 sigma)
#define BSTRIDE 12288  // padded bucket region: BCAP + 512 nodes * 8 pad slots

// ---------------- bf16 helpers ----------------

__device__ __forceinline__ float bf2f(unsigned short u) {
    unsigned x = ((unsigned)u) << 16;
    union { unsigned u; float f; } c; c.u = x; return c.f;
}
__device__ __forceinline__ unsigned short f2bf(float f) {   // round-to-nearest-even
    union { float f; unsigned u; } c; c.f = f;
    unsigned r = c.u + 0x7fffu + ((c.u >> 16) & 1u);
    return (unsigned short)(r >> 16);
}

// ================= utility =================

__global__ void zero_u32_kernel(unsigned* __restrict__ p, int n) {
    int i = blockIdx.x * blockDim.x + threadIdx.x;
    if (i < n) p[i] = 0u;
}

// zero the phantom row N of both y buffers (32 u32 words each)
__global__ void zero_dummy_kernel(unsigned* __restrict__ a, unsigned* __restrict__ b) {
    int t = threadIdx.x;
    if (t < 32) { a[t] = 0u; b[t] = 0u; }
}

// ================= feature fusion =================
// writes plain x into total (=d_out) and dis-premultiplied bf16 y into y0

__global__ void fuse_users_kernel(const float* __restrict__ feat,       // [U,15]
                                  const int* __restrict__ cidx,
                                  const int* __restrict__ sidx,
                                  const float* __restrict__ emb_w,      // [U,64]
                                  const float* __restrict__ Wn,         // [64,12]
                                  const float* __restrict__ bn,
                                  const float* __restrict__ Wv,         // [64,3]
                                  const float* __restrict__ bv,
                                  const float* __restrict__ color_w,    // [22,64]
                                  const float* __restrict__ size_w,     // [18,64]
                                  const float* __restrict__ dis,        // [N]
                                  float* __restrict__ total,            // [N,64]
                                  unsigned short* __restrict__ y0,      // [(N+1),64] bf16
                                  int U) {
    int t = blockIdx.x * blockDim.x + threadIdx.x;
    int u = t >> 6, d = t & 63;
    if (u >= U) return;
    const float* f = feat + (size_t)u * 15;
    float acc = emb_w[(size_t)u * EMB + d] + bn[d] + bv[d];
#pragma unroll
    for (int k = 0; k < 12; ++k) acc = fmaf(f[k], Wn[d * 12 + k], acc);
#pragma unroll
    for (int k = 0; k < 3; ++k) acc = fmaf(f[12 + k], Wv[d * 3 + k], acc);
    acc += color_w[(size_t)cidx[u] * EMB + d];
    acc += size_w[(size_t)sidx[u] * EMB + d];
    size_t o = (size_t)u * EMB + d;
    total[o] = acc;
    y0[o] = f2bf(acc * dis[u]);
}

__global__ void fuse_items_kernel(const float* __restrict__ feat,       // [I,17]
                                  const float* __restrict__ emb_w,      // [I,64]
                                  const float* __restrict__ Wn,         // [64,5]
                                  const float* __restrict__ bn,
                                  const float* __restrict__ Wv,         // [64,12]
                                  const float* __restrict__ bv,
                                  const float* __restrict__ dis,        // [N]
                                  float* __restrict__ total,
                                  unsigned short* __restrict__ y0,
                                  int I, int U) {
    int t = blockIdx.x * blockDim.x + threadIdx.x;
    int i = t >> 6, d = t & 63;
    if (i >= I) return;
    const float* f = feat + (size_t)i * 17;
    float acc = emb_w[(size_t)i * EMB + d] + bn[d] + bv[d];
#pragma unroll
    for (int k = 0; k < 5; ++k) acc = fmaf(f[k], Wn[d * 5 + k], acc);
#pragma unroll
    for (int k = 0; k < 12; ++k) acc = fmaf(f[5 + k], Wv[d * 12 + k], acc);
    int n = U + i;
    size_t o = (size_t)n * EMB + d;
    total[o] = acc;
    y0[o] = f2bf(acc * dis[n]);
}

// ================= bucketed CSR build =================
// pass 1: partition edges into NB col-range buckets (packed row<<9 | col&511)

__global__ __launch_bounds__(256) void partition_kernel(
        const int* __restrict__ row, const int* __restrict__ col,
        unsigned* __restrict__ bcursor, unsigned* __restrict__ bucketbuf,
        int E, int NB) {
    __shared__ unsigned h[NBMAX];
    __shared__ unsigned wbase[NBMAX];
    const int t = threadIdx.x;
    const long chunk = (long)blockIdx.x * BCAP;

    for (int i = t; i < NB; i += 256) h[i] = 0u;
    __syncthreads();
    for (int it = 0; it < BCAP / 256; ++it) {
        long e = chunk + (long)it * 256 + t;
        if (e < E) atomicAdd(&h[((unsigned)col[e]) >> 9], 1u);
    }
    __syncthreads();
    for (int i = t; i < NB; i += 256) {
        unsigned c = h[i];
        wbase[i] = c ? atomicAdd(&bcursor[i], c) : 0u;
    }
    __syncthreads();
    for (int i = t; i < NB; i += 256) h[i] = 0u;
    __syncthreads();
    for (int it = 0; it < BCAP / 256; ++it) {
        long e = chunk + (long)it * 256 + t;
        if (e < E) {
            unsigned c = (unsigned)col[e];
            unsigned b = c >> 9;
            unsigned lpos = atomicAdd(&h[b], 1u);
            unsigned pos = wbase[b] + lpos;
            if (pos < BCAP)
                bucketbuf[(size_t)b * BCAP + pos] = (((unsigned)row[e]) << 9) | (c & 511u);
        }
    }
}

// pass 2: one WG per bucket -> begs/ende (pad-8), dis, srcidx (+ phantom pads)

__global__ __launch_bounds__(256) void bucket_csr_kernel(
        const unsigned* __restrict__ bcursor,   // final per-bucket counts
        const unsigned* __restrict__ bucketbuf,
        unsigned* __restrict__ begs, unsigned* __restrict__ ende,
        float* __restrict__ dis, unsigned* __restrict__ srcidx,
        int N, int NB) {
    const int b = blockIdx.x;
    const int t = threadIdx.x;
    __shared__ unsigned hist[512];
    __shared__ unsigned ps[256];

    const unsigned base = (unsigned)b * BSTRIDE;
    unsigned cntb = bcursor[b];
    if (cntb > BCAP) cntb = BCAP;

    hist[2 * t] = 0u; hist[2 * t + 1] = 0u;
    __syncthreads();
    const unsigned* buf = bucketbuf + (size_t)b * BCAP;
    for (unsigned j = t; j < cntb; j += 256) atomicAdd(&hist[buf[j] & 511u], 1u);
    __syncthreads();

    unsigned h0 = hist[2 * t], h1 = hist[2 * t + 1];
    unsigned c0p = (h0 + 7u) & ~7u, c1p = (h1 + 7u) & ~7u;   // pad to multiple of 8
    ps[t] = c0p + c1p;
    __syncthreads();
    for (int off = 1; off < 256; off <<= 1) {
        unsigned y = (t >= off) ? ps[t - off] : 0u;
        __syncthreads();
        ps[t] += y;
        __syncthreads();
    }
    unsigned pexcl = ps[t] - (c0p + c1p);
    unsigned beg0 = base + pexcl, beg1 = beg0 + c0p;

    int n0 = (b << 9) + 2 * t, n1 = n0 + 1;
    if (n0 < N) {
        begs[n0] = beg0; ende[n0] = beg0 + c0p;
        dis[n0] = h0 ? rsqrtf((float)h0) : 0.f;
        for (unsigned k = h0; k < c0p; ++k) srcidx[beg0 + k] = (unsigned)N;  // phantom pads
    }
    if (n1 < N) {
        begs[n1] = beg1; ende[n1] = beg1 + c1p;
        dis[n1] = h1 ? rsqrtf((float)h1) : 0.f;
        for (unsigned k = h1; k < c1p; ++k) srcidx[beg1 + k] = (unsigned)N;
    }
    __syncthreads();

    // scatter via LDS cursors (absolute positions); writes stay in one bucket region
    hist[2 * t] = beg0; hist[2 * t + 1] = beg1;
    __syncthreads();
    for (unsigned j = t; j < cntb; j += 256) {
        unsigned p = buf[j];
        unsigned pos = atomicAdd(&hist[p & 511u], 1u);
        srcidx[pos] = p >> 9;
    }
}

// ================= propagation (gather, bf16 rows, no conditionals) =================
// src holds bf16 y = dis * acc_prev, row N is zeros. One 64-lane wave per node.

__global__ __launch_bounds__(256) void gather_propagate_kernel(
        const unsigned* __restrict__ begs, const unsigned* __restrict__ ende,
        const float* __restrict__ dis, const unsigned short* __restrict__ src,
        const unsigned* __restrict__ srcidx,
        unsigned short* __restrict__ ynext, float* __restrict__ total,
        float scale, int N, int store) {
    int n = blockIdx.x * 4 + (threadIdx.x >> 6);
    if (n >= N) return;
    int d = threadIdx.x & 63;
    unsigned beg = begs[n], endp = ende[n];
    float sum = 0.f;
    for (unsigned j = beg; j < endp; j += 8) {
        unsigned r[8];
#pragma unroll
        for (int k = 0; k < 8; ++k)
            r[k] = __builtin_nontemporal_load(&srcidx[j + k]);
        float v[8];
#pragma unroll
        for (int k = 0; k < 8; ++k)
            v[k] = bf2f(src[r[k] * 64u + (unsigned)d]);
        sum += ((v[0] + v[1]) + (v[2] + v[3])) + ((v[4] + v[5]) + (v[6] + v[7]));
    }
    float dn = dis[n];
    float a = dn * sum;
    size_t o = (size_t)n * EMB + d;
    float tv = __builtin_nontemporal_load(&total[o]);
    __builtin_nontemporal_store((tv + a) * scale, &total[o]);
    if (store) ynext[o] = f2bf(dn * a);
}

// ================= launch =================

extern "C" void kernel_launch(void* const* d_in, const int* in_sizes, int n_in,
                              void* d_out, int out_size, void* d_ws, size_t ws_size,
                              hipStream_t stream) {
    const int*   edge       = (const int*)d_in[0];
    const float* user_feat  = (const float*)d_in[1];
    const int*   cidx       = (const int*)d_in[2];
    const int*   sidx       = (const int*)d_in[3];
    const float* item_feat  = (const float*)d_in[4];
    const float* user_emb_w = (const float*)d_in[5];
    const float* item_emb_w = (const float*)d_in[6];
    const float* uWn        = (const float*)d_in[7];
    const float* ubn        = (const float*)d_in[8];
    const float* uWv        = (const float*)d_in[9];
    const float* ubv        = (const float*)d_in[10];
    const float* color_w    = (const float*)d_in[11];
    const float* size_w     = (const float*)d_in[12];
    const float* iWn        = (const float*)d_in[13];
    const float* ibn        = (const float*)d_in[14];
    const float* iWv        = (const float*)d_in[15];
    const float* ibv        = (const float*)d_in[16];

    const int E = in_sizes[0] / 2;
    const int U = in_sizes[5] / EMB;
    const int I = in_sizes[6] / EMB;
    const int N = U + I;
    const int NB = (N + 511) >> 9;     // 293 buckets

    const int* row = edge;
    const int* col = edge + E;

    float* total = (float*)d_out;      // running sum x + a1 + a2 + a3

    // workspace layout
    unsigned short* yA      = (unsigned short*)d_ws;          // [(N+1)*64] bf16
    unsigned short* yB      = yA + (size_t)(N + 1) * EMB;     // [(N+1)*64] bf16
    unsigned*       bucketbuf = (unsigned*)yB;                // [NB*BCAP] aliases yB (disjoint lifetime)
    unsigned*       srcidx  = (unsigned*)(yB + (size_t)(N + 1) * EMB);  // [NB*BSTRIDE]
    unsigned*       begs    = srcidx + (size_t)NB * BSTRIDE;  // [N]
    unsigned*       ende    = begs + N;                       // [N]
    float*          dis     = (float*)(ende + N);             // [N]
    unsigned*       bcursor = (unsigned*)(dis + N);           // [NB]

    const int TB = 256;

    // 1. CSR build (also produces dis)
    zero_u32_kernel<<<(NB + TB - 1) / TB, TB, 0, stream>>>(bcursor, NB);
    const int gP = (E + BCAP - 1) / BCAP;
    partition_kernel<<<gP, TB, 0, stream>>>(row, col, bcursor, bucketbuf, E, NB);
    bucket_csr_kernel<<<NB, TB, 0, stream>>>(bcursor, bucketbuf, begs, ende, dis,
                                             srcidx, N, NB);
    // phantom row N of both y buffers = 0 (after bucketbuf's lifetime ends)
    zero_dummy_kernel<<<1, 64, 0, stream>>>((unsigned*)(yA + (size_t)N * EMB),
                                            (unsigned*)(yB + (size_t)N * EMB));

    // 2. fuse features: total = x, yA = bf16(dis*x)
    {
        int gU = (int)(((long)U * EMB + TB - 1) / TB);
        fuse_users_kernel<<<gU, TB, 0, stream>>>(user_feat, cidx, sidx, user_emb_w,
                                                 uWn, ubn, uWv, ubv, color_w, size_w,
                                                 dis, total, yA, U);
        int gI = (int)(((long)I * EMB + TB - 1) / TB);
        fuse_items_kernel<<<gI, TB, 0, stream>>>(item_feat, item_emb_w,
                                                 iWn, ibn, iWv, ibv,
                                                 dis, total, yA, I, U);
    }

    // 3. three propagation layers (gather form), total-accumulate fused
    const int gG = (N + 3) / 4;   // 4 nodes (waves) per block
    gather_propagate_kernel<<<gG, TB, 0, stream>>>(begs, ende, dis, yA, srcidx, yB, total,
                                                   1.0f, N, 1);
    gather_propagate_kernel<<<gG, TB, 0, stream>>>(begs, ende, dis, yB, srcidx, yA, total,
                                                   1.0f, N, 1);
    gather_propagate_kernel<<<gG, TB, 0, stream>>>(begs, ende, dis, yA, srcidx, yB, total,
                                                   0.25f, N, 0);

    (void)n_in; (void)out_size; (void)ws_size;
}

// Round 6
// 327.393 us; speedup vs baseline: 4.7024x; 1.0934x over previous
//
#include <hip/hip_runtime.h>

#define EMB 64
#define NBMAX 512      // max buckets (NB = ceil(N/512) = 293 for N=150000)
#define BCAP 8192      // bucket edge capacity (mean 6827, +16 sigma)
#define BSTRIDE 12288  // padded bucket region: BCAP + 512 nodes * 8 pad slots

typedef float f32x2 __attribute__((ext_vector_type(2)));

// ---------------- bf16 helpers ----------------

__device__ __forceinline__ unsigned short f2bf(float f) {   // round-to-nearest-even
    union { float f; unsigned u; } c; c.f = f;
    unsigned r = c.u + 0x7fffu + ((c.u >> 16) & 1u);
    return (unsigned short)(r >> 16);
}
__device__ __forceinline__ float bflo(unsigned u) {         // low bf16 -> f32
    union { unsigned u; float f; } c; c.u = u << 16; return c.f;
}
__device__ __forceinline__ float bfhi(unsigned u) {         // high bf16 -> f32
    union { unsigned u; float f; } c; c.u = u & 0xffff0000u; return c.f;
}

// ================= utility =================

__global__ void zero_u32_kernel(unsigned* __restrict__ p, int n) {
    int i = blockIdx.x * blockDim.x + threadIdx.x;
    if (i < n) p[i] = 0u;
}

// zero the phantom row N of both y buffers (32 u32 words each)
__global__ void zero_dummy_kernel(unsigned* __restrict__ a, unsigned* __restrict__ b) {
    int t = threadIdx.x;
    if (t < 32) { a[t] = 0u; b[t] = 0u; }
}

// ================= feature fusion =================
// writes plain x into total (=d_out) and dis-premultiplied bf16 y into y0

__global__ void fuse_users_kernel(const float* __restrict__ feat,       // [U,15]
                                  const int* __restrict__ cidx,
                                  const int* __restrict__ sidx,
                                  const float* __restrict__ emb_w,      // [U,64]
                                  const float* __restrict__ Wn,         // [64,12]
                                  const float* __restrict__ bn,
                                  const float* __restrict__ Wv,         // [64,3]
                                  const float* __restrict__ bv,
                                  const float* __restrict__ color_w,    // [22,64]
                                  const float* __restrict__ size_w,     // [18,64]
                                  const float* __restrict__ dis,        // [N]
                                  float* __restrict__ total,            // [N,64]
                                  unsigned short* __restrict__ y0,      // [(N+1),64] bf16
                                  int U) {
    int t = blockIdx.x * blockDim.x + threadIdx.x;
    int u = t >> 6, d = t & 63;
    if (u >= U) return;
    const float* f = feat + (size_t)u * 15;
    float acc = emb_w[(size_t)u * EMB + d] + bn[d] + bv[d];
#pragma unroll
    for (int k = 0; k < 12; ++k) acc = fmaf(f[k], Wn[d * 12 + k], acc);
#pragma unroll
    for (int k = 0; k < 3; ++k) acc = fmaf(f[12 + k], Wv[d * 3 + k], acc);
    acc += color_w[(size_t)cidx[u] * EMB + d];
    acc += size_w[(size_t)sidx[u] * EMB + d];
    size_t o = (size_t)u * EMB + d;
    total[o] = acc;
    y0[o] = f2bf(acc * dis[u]);
}

__global__ void fuse_items_kernel(const float* __restrict__ feat,       // [I,17]
                                  const float* __restrict__ emb_w,      // [I,64]
                                  const float* __restrict__ Wn,         // [64,5]
                                  const float* __restrict__ bn,
                                  const float* __restrict__ Wv,         // [64,12]
                                  const float* __restrict__ bv,
                                  const float* __restrict__ dis,        // [N]
                                  float* __restrict__ total,
                                  unsigned short* __restrict__ y0,
                                  int I, int U) {
    int t = blockIdx.x * blockDim.x + threadIdx.x;
    int i = t >> 6, d = t & 63;
    if (i >= I) return;
    const float* f = feat + (size_t)i * 17;
    float acc = emb_w[(size_t)i * EMB + d] + bn[d] + bv[d];
#pragma unroll
    for (int k = 0; k < 5; ++k) acc = fmaf(f[k], Wn[d * 5 + k], acc);
#pragma unroll
    for (int k = 0; k < 12; ++k) acc = fmaf(f[5 + k], Wv[d * 12 + k], acc);
    int n = U + i;
    size_t o = (size_t)n * EMB + d;
    total[o] = acc;
    y0[o] = f2bf(acc * dis[n]);
}

// ================= bucketed CSR build =================
// pass 1: partition edges into NB col-range buckets (packed row<<9 | col&511)

__global__ __launch_bounds__(256) void partition_kernel(
        const int* __restrict__ row, const int* __restrict__ col,
        unsigned* __restrict__ bcursor, unsigned* __restrict__ bucketbuf,
        int E, int NB) {
    __shared__ unsigned h[NBMAX];
    __shared__ unsigned wbase[NBMAX];
    const int t = threadIdx.x;
    const long chunk = (long)blockIdx.x * BCAP;

    for (int i = t; i < NB; i += 256) h[i] = 0u;
    __syncthreads();
    for (int it = 0; it < BCAP / 256; ++it) {
        long e = chunk + (long)it * 256 + t;
        if (e < E) atomicAdd(&h[((unsigned)col[e]) >> 9], 1u);
    }
    __syncthreads();
    for (int i = t; i < NB; i += 256) {
        unsigned c = h[i];
        wbase[i] = c ? atomicAdd(&bcursor[i], c) : 0u;
    }
    __syncthreads();
    for (int i = t; i < NB; i += 256) h[i] = 0u;
    __syncthreads();
    for (int it = 0; it < BCAP / 256; ++it) {
        long e = chunk + (long)it * 256 + t;
        if (e < E) {
            unsigned c = (unsigned)col[e];
            unsigned b = c >> 9;
            unsigned lpos = atomicAdd(&h[b], 1u);
            unsigned pos = wbase[b] + lpos;
            if (pos < BCAP)
                bucketbuf[(size_t)b * BCAP + pos] = (((unsigned)row[e]) << 9) | (c & 511u);
        }
    }
}

// pass 2: one WG per bucket -> begs/ende (pad-8), dis, srcidx (+ phantom pads)

__global__ __launch_bounds__(256) void bucket_csr_kernel(
        const unsigned* __restrict__ bcursor,   // final per-bucket counts
        const unsigned* __restrict__ bucketbuf,
        unsigned* __restrict__ begs, unsigned* __restrict__ ende,
        float* __restrict__ dis, unsigned* __restrict__ srcidx,
        int N, int NB) {
    const int b = blockIdx.x;
    const int t = threadIdx.x;
    __shared__ unsigned hist[512];
    __shared__ unsigned ps[256];

    const unsigned base = (unsigned)b * BSTRIDE;
    unsigned cntb = bcursor[b];
    if (cntb > BCAP) cntb = BCAP;

    hist[2 * t] = 0u; hist[2 * t + 1] = 0u;
    __syncthreads();
    const unsigned* buf = bucketbuf + (size_t)b * BCAP;
    for (unsigned j = t; j < cntb; j += 256) atomicAdd(&hist[buf[j] & 511u], 1u);
    __syncthreads();

    unsigned h0 = hist[2 * t], h1 = hist[2 * t + 1];
    unsigned c0p = (h0 + 7u) & ~7u, c1p = (h1 + 7u) & ~7u;   // pad to multiple of 8
    ps[t] = c0p + c1p;
    __syncthreads();
    for (int off = 1; off < 256; off <<= 1) {
        unsigned y = (t >= off) ? ps[t - off] : 0u;
        __syncthreads();
        ps[t] += y;
        __syncthreads();
    }
    unsigned pexcl = ps[t] - (c0p + c1p);
    unsigned beg0 = base + pexcl, beg1 = beg0 + c0p;

    int n0 = (b << 9) + 2 * t, n1 = n0 + 1;
    if (n0 < N) {
        begs[n0] = beg0; ende[n0] = beg0 + c0p;
        dis[n0] = h0 ? rsqrtf((float)h0) : 0.f;
        for (unsigned k = h0; k < c0p; ++k) srcidx[beg0 + k] = (unsigned)N;  // phantom pads
    }
    if (n1 < N) {
        begs[n1] = beg1; ende[n1] = beg1 + c1p;
        dis[n1] = h1 ? rsqrtf((float)h1) : 0.f;
        for (unsigned k = h1; k < c1p; ++k) srcidx[beg1 + k] = (unsigned)N;
    }
    __syncthreads();

    // scatter via LDS cursors (absolute positions); writes stay in one bucket region
    hist[2 * t] = beg0; hist[2 * t + 1] = beg1;
    __syncthreads();
    for (unsigned j = t; j < cntb; j += 256) {
        unsigned p = buf[j];
        unsigned pos = atomicAdd(&hist[p & 511u], 1u);
        srcidx[pos] = p >> 9;
    }
}

// ================= propagation =================
// y rows viewed as 32 u32 words (bf16x2). One wave per node; lane = (half, m):
// lanes 0-31 process even edge slots, 32-63 odd slots; each lane covers dims
// (2m, 2m+1). One wave-load instruction covers TWO source rows (256B).

__global__ __launch_bounds__(256) void gather_propagate_kernel(
        const unsigned* __restrict__ begs, const unsigned* __restrict__ ende,
        const float* __restrict__ dis, const unsigned* __restrict__ src,   // [(N+1)*32]
        const unsigned* __restrict__ srcidx,
        unsigned* __restrict__ ynext,      // [(N+1)*32]
        f32x2* __restrict__ total,         // [N*32]
        float scale, int N, int store) {
    int n = blockIdx.x * 4 + (threadIdx.x >> 6);
    if (n >= N) return;
    int lane = threadIdx.x & 63;
    int half = lane >> 5;              // which edge slot parity this lane handles
    unsigned m = (unsigned)(lane & 31);          // dim-pair index
    unsigned beg = begs[n], endp = ende[n];
    float s0 = 0.f, s1 = 0.f;
    for (unsigned j = beg; j < endp; j += 8) {
        uint4 i0 = *reinterpret_cast<const uint4*>(&srcidx[j]);
        uint4 i1 = *reinterpret_cast<const uint4*>(&srcidx[j + 4]);
        unsigned r0 = half ? i0.y : i0.x;   // slots j+1 / j
        unsigned r1 = half ? i0.w : i0.z;   // slots j+3 / j+2
        unsigned r2 = half ? i1.y : i1.x;   // slots j+5 / j+4
        unsigned r3 = half ? i1.w : i1.z;   // slots j+7 / j+6
        unsigned u0 = src[r0 * 32u + m];
        unsigned u1 = src[r1 * 32u + m];
        unsigned u2 = src[r2 * 32u + m];
        unsigned u3 = src[r3 * 32u + m];
        s0 += (bflo(u0) + bflo(u1)) + (bflo(u2) + bflo(u3));
        s1 += (bfhi(u0) + bfhi(u1)) + (bfhi(u2) + bfhi(u3));
    }
    // combine the two edge-halves
    s0 += __shfl_xor(s0, 32);
    s1 += __shfl_xor(s1, 32);
    if (lane < 32) {
        float dn = dis[n];
        float a0 = dn * s0, a1 = dn * s1;
        size_t o = (size_t)n * 32 + m;
        f32x2 tv = __builtin_nontemporal_load(&total[o]);
        f32x2 nv; nv.x = (tv.x + a0) * scale; nv.y = (tv.y + a1) * scale;
        __builtin_nontemporal_store(nv, &total[o]);
        if (store) {
            unsigned pk = (unsigned)f2bf(dn * a0) | ((unsigned)f2bf(dn * a1) << 16);
            __builtin_nontemporal_store(pk, &ynext[o]);
        }
    }
}

// ================= launch =================

extern "C" void kernel_launch(void* const* d_in, const int* in_sizes, int n_in,
                              void* d_out, int out_size, void* d_ws, size_t ws_size,
                              hipStream_t stream) {
    const int*   edge       = (const int*)d_in[0];
    const float* user_feat  = (const float*)d_in[1];
    const int*   cidx       = (const int*)d_in[2];
    const int*   sidx       = (const int*)d_in[3];
    const float* item_feat  = (const float*)d_in[4];
    const float* user_emb_w = (const float*)d_in[5];
    const float* item_emb_w = (const float*)d_in[6];
    const float* uWn        = (const float*)d_in[7];
    const float* ubn        = (const float*)d_in[8];
    const float* uWv        = (const float*)d_in[9];
    const float* ubv        = (const float*)d_in[10];
    const float* color_w    = (const float*)d_in[11];
    const float* size_w     = (const float*)d_in[12];
    const float* iWn        = (const float*)d_in[13];
    const float* ibn        = (const float*)d_in[14];
    const float* iWv        = (const float*)d_in[15];
    const float* ibv        = (const float*)d_in[16];

    const int E = in_sizes[0] / 2;
    const int U = in_sizes[5] / EMB;
    const int I = in_sizes[6] / EMB;
    const int N = U + I;
    const int NB = (N + 511) >> 9;     // 293 buckets

    const int* row = edge;
    const int* col = edge + E;

    float* total = (float*)d_out;      // running sum x + a1 + a2 + a3

    // workspace layout
    unsigned short* yA      = (unsigned short*)d_ws;          // [(N+1)*64] bf16
    unsigned short* yB      = yA + (size_t)(N + 1) * EMB;     // [(N+1)*64] bf16
    unsigned*       bucketbuf = (unsigned*)yB;                // [NB*BCAP] aliases yB (disjoint lifetime)
    unsigned*       srcidx  = (unsigned*)(yB + (size_t)(N + 1) * EMB);  // [NB*BSTRIDE]
    unsigned*       begs    = srcidx + (size_t)NB * BSTRIDE;  // [N]
    unsigned*       ende    = begs + N;                       // [N]
    float*          dis     = (float*)(ende + N);             // [N]
    unsigned*       bcursor = (unsigned*)(dis + N);           // [NB]

    const int TB = 256;

    // 1. CSR build (also produces dis)
    zero_u32_kernel<<<(NB + TB - 1) / TB, TB, 0, stream>>>(bcursor, NB);
    const int gP = (E + BCAP - 1) / BCAP;
    partition_kernel<<<gP, TB, 0, stream>>>(row, col, bcursor, bucketbuf, E, NB);
    bucket_csr_kernel<<<NB, TB, 0, stream>>>(bcursor, bucketbuf, begs, ende, dis,
                                             srcidx, N, NB);
    // phantom row N of both y buffers = 0 (after bucketbuf's lifetime ends)
    zero_dummy_kernel<<<1, 64, 0, stream>>>((unsigned*)(yA + (size_t)N * EMB),
                                            (unsigned*)(yB + (size_t)N * EMB));

    // 2. fuse features: total = x, yA = bf16(dis*x)
    {
        int gU = (int)(((long)U * EMB + TB - 1) / TB);
        fuse_users_kernel<<<gU, TB, 0, stream>>>(user_feat, cidx, sidx, user_emb_w,
                                                 uWn, ubn, uWv, ubv, color_w, size_w,
                                                 dis, total, yA, U);
        int gI = (int)(((long)I * EMB + TB - 1) / TB);
        fuse_items_kernel<<<gI, TB, 0, stream>>>(item_feat, item_emb_w,
                                                 iWn, ibn, iWv, ibv,
                                                 dis, total, yA, I, U);
    }

    // 3. three propagation layers (gather form), total-accumulate fused
    const int gG = (N + 3) / 4;   // 4 nodes (waves) per block
    gather_propagate_kernel<<<gG, TB, 0, stream>>>(begs, ende, dis, (const unsigned*)yA,
                                                   srcidx, (unsigned*)yB, (f32x2*)total,
                                                   1.0f, N, 1);
    gather_propagate_kernel<<<gG, TB, 0, stream>>>(begs, ende, dis, (const unsigned*)yB,
                                                   srcidx, (unsigned*)yA, (f32x2*)total,
                                                   1.0f, N, 1);
    gather_propagate_kernel<<<gG, TB, 0, stream>>>(begs, ende, dis, (const unsigned*)yA,
                                                   srcidx, (unsigned*)yB, (f32x2*)total,
                                                   0.25f, N, 0);

    (void)n_in; (void)out_size; (void)ws_size;
}